// Round 6
// baseline (247.254 us; speedup 1.0000x reference)
//
#include <hip/hip_runtime.h>

// PositionEncoder: out[b][s][0:512] = x[b][s][:], out[b][s][512:517] = enc(s)
// B=64, S=1024, D=512, H=W=32.  enc[k] = ((x>>(4-k))&1) & !((y>>(4-k))&1),
// y=s>>5, x=s&31  (verified absmax=0.0 R1-R3, R5-R7).
//
// Round-9 (R8 compile fix): R8 never compiled -- one static_assert was
// arithmetic nonsense (kGroups*kDOut*4 == kRows*kDOut*4; kGroups=kRows/4).
// Intended invariant: kGroups * kDOut == kTotalF4 (16384*517 = 8,470,528).
// Kernel body unchanged from R8; theory untested until now.
//
// Structure: persistent waves + double-buffered wave-private image + counted
// vmcnt prefetch pipeline (T3/T4 pattern).
// R7 post-mortem (first pe_kernel counters): 82 us, FETCH 135.6 MB (ideal
// 1.01x), WRITE ~135 MB (ideal), bank-conflict 2.1M cyc (~4%), VALU 9%,
// occupancy 32% -> NOT traffic/VALU/conflict bound; 3.3 TB/s = 52% of copy
// ceiling because each wave did ONE group: load burst -> vmcnt(0) full drain
// -> process -> exit, 4096 transient blocks, no steady state, HBM idles
// between dispatch batches.
// Fix: 512 blocks (2/CU, ALL resident; 512*4*8 = 16384 groups exact), each
// wave loops over 8 groups with 2x 8KB buffers; loads for group i+1 fly
// while group i is processed; waits are counted (never vmcnt(0) in loop).
//
// vmcnt accounting (static, per wave): 8 global_load_lds + 9 nt stores per
// group, no other VMEM (no spills at 44 VGPR; boundary path is LDS-only).
//   steady iter i: stream ... L(i)x8, S(i-1)x9, L(i+1)x8 [wait] S(i)x9 ...
//     vmcnt(17) = retire all but newest 17 (= S(i-1)+L(i+1)) => L(i) done,
//     even if older stores linger (they are older than L(i), retired too).
//   prologue: L(0)x8, L(1)x8 [vmcnt(8)] => L(0) done.
//   epilogue: L(7)x8, S(6)x9 outstanding [vmcnt(9)] => L(7) done.
// Store count proof: k=0..7 full waves (j=k*64+lane<=511<517); k=8 lanes 0-4
// active in EVERY wave -> exactly 9 store instructions issue per group.
//
// Evidence log: R1 scalar 233.7 | R2 LDS 234.2 | R3 LDS+nt 224.9 (best) |
// R4 OOB crash | R5 dual-load 236.2 | R6 shfl 231.2 | R7 wave-auto 238.8
// (kernel 82.5 us, ideal traffic, latency-bound) | R8 static_assert typo.
// R9 prediction: kernel ~48-55 us, dur ~205-212.

typedef float f32x4 __attribute__((ext_vector_type(4)));

#define AS1 __attribute__((address_space(1)))
#define AS3 __attribute__((address_space(3)))

static constexpr unsigned kD       = 512;
static constexpr unsigned kDOut    = 517;
static constexpr unsigned kRows    = 64u * 1024u;            // 65536
static constexpr unsigned kTotalF4 = kRows * kDOut / 4u;     // 8,470,528
static constexpr unsigned kGroups  = kRows / 4u;             // 16384 (4-row groups)
static constexpr unsigned kThreads = 256;
static constexpr unsigned kWaves   = kThreads / 64u;         // 4
static constexpr unsigned kNG      = 8;                      // groups per wave
static constexpr unsigned kBlocks  = kGroups / (kWaves * kNG);  // 512 exact
static constexpr unsigned kImgF    = 4u * kD;                // 2048 floats/group

static_assert(kBlocks * kWaves * kNG == kGroups, "exact persistent grid");
static_assert(kGroups * kDOut == kTotalF4, "517 out-f4 per 4-row group");
static_assert(sizeof(float) * kWaves * 2u * kImgF == 65536u, "64KB LDS");

__global__ __launch_bounds__(kThreads) void pe_kernel(
    const float* __restrict__ x, float* __restrict__ out) {
  __shared__ __align__(16) float lds[kWaves][2][kImgF];      // 64 KB -> 2 blk/CU
  const unsigned t    = threadIdx.x;
  const unsigned lane = t & 63u;
  const unsigned w    = t >> 6;
  const unsigned g0   = (blockIdx.x * kWaves + w) * kNG;     // first group

  const f32x4* __restrict__ x4 = reinterpret_cast<const f32x4*>(x);
  f32x4* __restrict__ o4       = reinterpret_cast<f32x4*>(out);

  // ---- issue the 8 global_load_lds (1 KB each) for group g0+i ----
  // lane l of call k loads x-f4 ((g0+i)*512 + k*64 + l); HW writes LDS at
  // (uniform base) + lane*16 -> linear x-layout of rows [4g, 4g+4).
  auto STAGE = [&](unsigned i) {
    const f32x4* src = x4 + (size_t)(g0 + i) * (kImgF / 4u) + lane;
    float* dst = &lds[w][i & 1u][0];
#pragma unroll
    for (unsigned k = 0; k < 8u; ++k) {
      __builtin_amdgcn_global_load_lds((const AS1 void*)(src + k * 64u),
                                       (AS3 void*)(dst + k * 256u), 16, 0, 0);
    }
  };

  // ---- realigned LDS reads -> aligned contiguous nt f4 stores (9/lane) ----
  auto PROCESS = [&](unsigned i) {
    const unsigned g  = g0 + i;
    const unsigned R0 = g * 4u;                              // first global row
    const float* img = &lds[w][i & 1u][0];
    f32x4* og = o4 + (size_t)g * kDOut;                      // group = 517 f4 exact
#pragma unroll
    for (unsigned k = 0; k < 9u; ++k) {
      const unsigned j = k * 64u + lane;                     // out-f4 in group
      if (j < kDOut) {                                       // k=8: lanes 0..4
        const unsigned o  = j * 4u;                          // float in group
        const unsigned r_ = o / kDOut;                       // row 0..3
        const unsigned c  = o - r_ * kDOut;                  // col 0..516
        f32x4 v;
        if (c <= kD - 4u) {
          // fast path (509/517): 4 consecutive x floats, same row
          const unsigned xb = r_ * kD + c;
          v.x = img[xb]; v.y = img[xb + 1u]; v.z = img[xb + 2u]; v.w = img[xb + 3u];
        } else {
          // boundary (8/group): may cross row and/or hit enc cols; LDS-only
#pragma unroll
          for (unsigned e = 0; e < 4u; ++e) {
            const unsigned oo = o + e;
            const unsigned rr = oo / kDOut;
            const unsigned cc = oo - rr * kDOut;
            float val;
            if (cc < kD) {
              val = img[rr * kD + cc];
            } else {
              const unsigned kk   = cc - kD;                 // 0..4
              const unsigned srow = (R0 + rr) & 1023u;
              const unsigned xx = srow & 31u, yy = srow >> 5, sh = 4u - kk;
              val = (float)(((xx >> sh) & 1u) & ((~(yy >> sh)) & 1u));
            }
            v[e] = val;
          }
        }
        __builtin_nontemporal_store(v, &og[j]);
      }
    }
  };

  // ---- pipeline: prefetch depth 1, counted waits, no barriers ----
  STAGE(0);
  STAGE(1);
  asm volatile("s_waitcnt vmcnt(8)" ::: "memory");
  __builtin_amdgcn_sched_barrier(0);
  PROCESS(0);
#pragma unroll
  for (unsigned i = 1; i < kNG - 1u; ++i) {
    STAGE(i + 1u);
    asm volatile("s_waitcnt vmcnt(17)" ::: "memory");
    __builtin_amdgcn_sched_barrier(0);
    PROCESS(i);
  }
  asm volatile("s_waitcnt vmcnt(9)" ::: "memory");
  __builtin_amdgcn_sched_barrier(0);
  PROCESS(kNG - 1u);
}

extern "C" void kernel_launch(void* const* d_in, const int* in_sizes, int n_in,
                              void* d_out, int out_size, void* d_ws,
                              size_t ws_size, hipStream_t stream) {
  const float* x = (const float*)d_in[0];
  float* out = (float*)d_out;
  // 512 blocks = 2/CU, all resident; 512 * 4 waves * 8 groups = 16384 groups
  pe_kernel<<<dim3(kBlocks), dim3(kThreads), 0, stream>>>(x, out);
}

// Round 7
// 232.741 us; speedup vs baseline: 1.0624x; 1.0624x over previous
//
#include <hip/hip_runtime.h>

// PositionEncoder: out[b][s][0:512] = x[b][s][:], out[b][s][512:517] = enc(s)
// B=64, S=1024, D=512, H=W=32.  enc[k] = ((x>>(4-k))&1) & !((y>>(4-k))&1),
// y=s>>5, x=s&31  (verified absmax=0.0 R1-R3, R5-R7, R9).
//
// Round-10: row-uniform direct copy. Zero LDS, zero barriers, max TLP.
// R7/R9 post-mortem: wave-private pipelining (global_load_lds + counted
// vmcnt) LOSES to brute TLP on a pure streaming op -- vmcnt retires in
// order, so any wait-for-load also waits for older stores, and low
// occupancy (2 blk/CU) can't cover it. R3 (32 waves/CU) remains best.
// R5/R6 post-mortem: per-f4 realign (div/switch/shfl/divergence) is the
// other failure mode.
// This round removes realignment entirely: each WAVE owns whole rows.
//  - r is wave-uniform: no magic-div, no switch, no divergent boundary.
//  - loads x4[r*128+lane]: perfectly aligned + self-coalesced (1 KB/instr).
//  - stores out+517r+4*lane: contiguous, dword-misaligned by (r&3) -> a
//    wave's 1 KB touches 17 vs 16 sectors (~6% store-side cost). Emitted as
//    a single global_store_dwordx4 (dword alignment suffices per ISA) via
//    inline asm so the compiler cannot split it on alignment grounds.
//  - enc: one predicated scalar nt store by lanes 0-4 (wave-uniform row).
//  - VMEM per row: 2 loads + 3 stores. No LDS round-trip at all.
// Occupancy: no LDS, ~40 VGPR -> 2048 blocks = 8 blk/CU = 32 waves/CU
// resident; 8 rows/wave grid-stride (8192 waves * 8 = 65536 exact).
//
// Evidence log: R1 scalar 233.7 | R2 LDS 234.2 | R3 LDS+nt 224.9 (best) |
// R4 OOB crash | R5 dual-load 236.2 | R6 shfl 231.2 | R7 wave-auto 238.8
// (kernel 82.5) | R8 assert typo | R9 persistent+vmcnt 247.3 (kernel 88,
// occupancy 16%, in-order vmcnt stalls on stores).
// R10 prediction: kernel ~46-55 us, conflicts 0, dur ~205-212.

typedef float f32x4 __attribute__((ext_vector_type(4)));

static constexpr unsigned kD       = 512;
static constexpr unsigned kDOut    = 517;
static constexpr unsigned kRows    = 64u * 1024u;        // 65536
static constexpr unsigned kThreads = 256;
static constexpr unsigned kWaves   = kThreads / 64u;     // 4
static constexpr unsigned kBlocks  = 2048;               // 8 per CU, all resident
static constexpr unsigned kWTotal  = kBlocks * kWaves;   // 8192 waves
static constexpr unsigned kRPW     = kRows / kWTotal;    // 8 rows per wave

static_assert(kRPW * kWTotal == kRows, "exact row coverage");

__global__ __launch_bounds__(kThreads) void pe_kernel(
    const float* __restrict__ x, float* __restrict__ out) {
  const unsigned t    = threadIdx.x;
  const unsigned lane = t & 63u;
  const unsigned w    = t >> 6;
  const unsigned wid  = blockIdx.x * kWaves + w;         // 0..8191
  const f32x4* __restrict__ x4 = reinterpret_cast<const f32x4*>(x);

#pragma unroll 2
  for (unsigned i = 0; i < kRPW; ++i) {
    const unsigned r = wid + i * kWTotal;                // wave-uniform row
    // ---- aligned nt vector loads: row r = 128 f4s, 2 per lane ----
    const f32x4 a = __builtin_nontemporal_load(&x4[(size_t)r * 128u + lane]);
    const f32x4 b = __builtin_nontemporal_load(&x4[(size_t)r * 128u + 64u + lane]);

    float* op = out + (size_t)r * kDOut;                 // row base (dword-aligned)
    float* p0 = op + 4u * lane;                          // bytes 16*lane + 4*(r&3)
    float* p1 = op + 256u + 4u * lane;
    // single-instruction 16B stores, dword-aligned is sufficient
    asm volatile("global_store_dwordx4 %0, %1, off nt" :: "v"(p0), "v"(a));
    asm volatile("global_store_dwordx4 %0, %1, off nt" :: "v"(p1), "v"(b));

    if (lane < 5u) {                                     // enc cols 512..516
      const unsigned s  = r & 1023u;                     // seq position
      const unsigned xx = s & 31u, yy = s >> 5, sh = 4u - lane;
      const float ev = (float)(((xx >> sh) & 1u) & ((~(yy >> sh)) & 1u));
      __builtin_nontemporal_store(ev, op + kD + lane);
    }
  }
}

extern "C" void kernel_launch(void* const* d_in, const int* in_sizes, int n_in,
                              void* d_out, int out_size, void* d_ws,
                              size_t ws_size, hipStream_t stream) {
  const float* x = (const float*)d_in[0];
  float* out = (float*)d_out;
  // 2048 blocks * 4 waves * 8 rows = 65536 rows, exact
  pe_kernel<<<dim3(kBlocks), dim3(kThreads), 0, stream>>>(x, out);
}